// Round 1
// baseline (357.410 us; speedup 1.0000x reference)
//
#include <hip/hip_runtime.h>
#include <stdint.h>

#define BB 4
#define CCH 64
#define NN 9216      // 96*96
#define NTILES 144   // NN/64

typedef unsigned short u16;
typedef __attribute__((ext_vector_type(8))) short bhalf8;   // 8 bf16 lanes of an MFMA operand
typedef __attribute__((ext_vector_type(4))) float f32x4;
typedef __attribute__((ext_vector_type(4))) u16 u16x4;
typedef __attribute__((ext_vector_type(8))) u16 u16x8;
typedef __attribute__((ext_vector_type(2))) unsigned int u32x2;

#define MFMA16(a, b, c) __builtin_amdgcn_mfma_f32_16x16x32_bf16((a), (b), (c), 0, 0, 0)

static __device__ __forceinline__ u16 f2bf(float f) {
  union { float f; unsigned u; } v; v.f = f;
  return (u16)((v.u + 0x7fffu + ((v.u >> 16) & 1u)) >> 16);  // RNE
}

// ---------------------------------------------------------------------------
// prep: blocks [0,256): per-(b,c) mean/rstd over 9216 spatial elems.
//       blocks [256,320): convert wq,wk,wv,wo (4*4096 f32) to bf16.
// ---------------------------------------------------------------------------
extern "C" __global__ __launch_bounds__(256) void prep_kernel(
    const float* __restrict__ x,
    const float* __restrict__ wq, const float* __restrict__ wk,
    const float* __restrict__ wv, const float* __restrict__ wo,
    float* __restrict__ mean, float* __restrict__ rstd, u16* __restrict__ wbf) {
  if (blockIdx.x >= 256) {
    int i = (blockIdx.x - 256) * 256 + threadIdx.x;  // 0..16383
    const float* src = (i < 4096) ? wq : (i < 8192) ? wk : (i < 12288) ? wv : wo;
    wbf[i] = f2bf(src[i & 4095]);
    return;
  }
  int idx = blockIdx.x;
  const float* p = x + (size_t)idx * NN;
  float s = 0.f, ss = 0.f;
  for (int i = threadIdx.x; i < NN; i += 256) { float v = p[i]; s += v; ss += v * v; }
#pragma unroll
  for (int o = 32; o > 0; o >>= 1) { s += __shfl_xor(s, o, 64); ss += __shfl_xor(ss, o, 64); }
  __shared__ float ls[4], lss[4];
  int w = threadIdx.x >> 6;
  if ((threadIdx.x & 63) == 0) { ls[w] = s; lss[w] = ss; }
  __syncthreads();
  if (threadIdx.x == 0) {
    s = ls[0] + ls[1] + ls[2] + ls[3];
    ss = lss[0] + lss[1] + lss[2] + lss[3];
    float m = s * (1.f / NN);
    float var = ss * (1.f / NN) - m * m;
    mean[idx] = m;
    rstd[idx] = rsqrtf(var + 1e-5f);
  }
}

// ---------------------------------------------------------------------------
// qkv: fused instance-norm + 1x1 convs via MFMA.
// Layouts produced: Qt,Kt = [B][N][64] bf16 (Q pre-scaled by 0.125*log2e),
//                   Vt    = [B][64][N] bf16 (no bias; bv folded into flash).
// Q/K use transposed orientation (A=weights) -> reg quad = 4 consecutive c.
// V uses normal orientation -> reg quad = 4 consecutive n.
// ---------------------------------------------------------------------------
extern "C" __global__ __launch_bounds__(256, 4) void qkv_kernel(
    const float* __restrict__ x,
    const float* __restrict__ mean, const float* __restrict__ rstd,
    const u16* __restrict__ wqb, const u16* __restrict__ wkb, const u16* __restrict__ wvb,
    const float* __restrict__ bq, const float* __restrict__ bk,
    u16* __restrict__ Qt, u16* __restrict__ Kt, u16* __restrict__ Vt) {
  __shared__ u16 hbuf[64 * 72];  // [n_local][c], padded rows (144B, 16B aligned)
  int b = blockIdx.x / NTILES, tile = blockIdx.x % NTILES;
  int n0 = tile * 64;
  int t = threadIdx.x;
  int w = t >> 6, lane = t & 63, q = lane >> 4, ln = lane & 15;
  const float QSCALE = 0.125f * 1.44269504088896340736f;  // C^-0.5 * log2(e)
#pragma unroll
  for (int rep = 0; rep < 16; rep++) {
    int c = rep * 4 + w;
    float v = x[(size_t)(b * 64 + c) * NN + n0 + lane];
    float h = (v - mean[b * 64 + c]) * rstd[b * 64 + c];
    hbuf[lane * 72 + c] = f2bf(h);
  }
  __syncthreads();
  int hrow = (16 * w + ln) * 72;
  bhalf8 hb0 = *(const bhalf8*)&hbuf[hrow + q * 8];
  bhalf8 hb1 = *(const bhalf8*)&hbuf[hrow + 32 + q * 8];
  size_t nrow = (size_t)(b * NN + n0 + 16 * w + ln) * 64;  // this lane's n-row in Qt/Kt
  // ---- Q (transposed orientation) ----
#pragma unroll
  for (int ct = 0; ct < 4; ct++) {
    int wrow = (16 * ct + ln) * 64;
    bhalf8 a0 = *(const bhalf8*)&wqb[wrow + q * 8];
    bhalf8 a1 = *(const bhalf8*)&wqb[wrow + 32 + q * 8];
    f32x4 d = {0.f, 0.f, 0.f, 0.f};
    d = MFMA16(a0, hb0, d);
    d = MFMA16(a1, hb1, d);
    f32x4 b4 = *(const f32x4*)&bq[16 * ct + 4 * q];
    u16x4 pk;
#pragma unroll
    for (int r = 0; r < 4; r++) pk[r] = f2bf((d[r] + b4[r]) * QSCALE);
    *(u16x4*)&Qt[nrow + 16 * ct + 4 * q] = pk;
  }
  // ---- K (transposed orientation) ----
#pragma unroll
  for (int ct = 0; ct < 4; ct++) {
    int wrow = (16 * ct + ln) * 64;
    bhalf8 a0 = *(const bhalf8*)&wkb[wrow + q * 8];
    bhalf8 a1 = *(const bhalf8*)&wkb[wrow + 32 + q * 8];
    f32x4 d = {0.f, 0.f, 0.f, 0.f};
    d = MFMA16(a0, hb0, d);
    d = MFMA16(a1, hb1, d);
    f32x4 b4 = *(const f32x4*)&bk[16 * ct + 4 * q];
    u16x4 pk;
#pragma unroll
    for (int r = 0; r < 4; r++) pk[r] = f2bf(d[r] + b4[r]);
    *(u16x4*)&Kt[nrow + 16 * ct + 4 * q] = pk;
  }
  // ---- V (normal orientation, no bias) ----
#pragma unroll
  for (int ct = 0; ct < 4; ct++) {
    int wrow = (16 * ct + ln) * 64;
    bhalf8 b0 = *(const bhalf8*)&wvb[wrow + q * 8];
    bhalf8 b1 = *(const bhalf8*)&wvb[wrow + 32 + q * 8];
    f32x4 d = {0.f, 0.f, 0.f, 0.f};
    d = MFMA16(hb0, b0, d);
    d = MFMA16(hb1, b1, d);
    u16x4 pk;
#pragma unroll
    for (int r = 0; r < 4; r++) pk[r] = f2bf(d[r]);
    *(u16x4*)&Vt[(size_t)(b * 64 + 16 * ct + ln) * NN + n0 + 16 * w + 4 * q] = pk;
  }
}

// ---------------------------------------------------------------------------
// flash: online-softmax attention. One block = 64 Q-rows (4 waves x 16).
// S^T orientation: softmax over keys = in-lane reduction + 2 shuffles;
// P^T exits in C-layout whose reg-quad = 4 consecutive m -> 8B LDS writes,
// and PV B-fragments are contiguous 16B LDS reads.
// Output Ot = [B][N][64] bf16, includes /l and +bv.
// ---------------------------------------------------------------------------
extern "C" __global__ __launch_bounds__(256, 4) void flash_kernel(
    const u16* __restrict__ Qt, const u16* __restrict__ Kt, const u16* __restrict__ Vt,
    const float* __restrict__ bv, u16* __restrict__ Ot) {
  __shared__ u16 kbuf[64 * 72];       // [m_local][c]
  __shared__ u16 vbuf[64 * 72];       // [c][m_local]
  __shared__ u16 pbuf[4 * 16 * 72];   // per-wave [n_local][m/4 blocks of 4 bf16]
  int b = blockIdx.x / NTILES, tile = blockIdx.x % NTILES;
  int t = threadIdx.x;
  int w = t >> 6, lane = t & 63, q = lane >> 4, ln = lane & 15;
  int n0w = tile * 64 + 16 * w;
  const u16* qp = Qt + (size_t)(b * NN + n0w + ln) * 64 + q * 8;
  bhalf8 qf0 = *(const bhalf8*)qp;
  bhalf8 qf1 = *(const bhalf8*)(qp + 32);
  f32x4 o[4];
#pragma unroll
  for (int i = 0; i < 4; i++) o[i] = (f32x4){0.f, 0.f, 0.f, 0.f};
  float m_i = -3.0e38f, l_i = 0.f;
  u16* pb = pbuf + w * (16 * 72);
  const u16* kb_g = Kt + (size_t)b * NN * 64;
  const u16* vb_g = Vt + (size_t)b * 64 * NN;
  int r0 = t >> 3, c0 = (t & 7) * 8;

  for (int m0 = 0; m0 < NN; m0 += 64) {
    // stage K tile (contiguous 8KB) and V tile (64 rows x 128B)
    *(u16x8*)&kbuf[r0 * 72 + c0]        = *(const u16x8*)(kb_g + (size_t)m0 * 64 + t * 8);
    *(u16x8*)&kbuf[(r0 + 32) * 72 + c0] = *(const u16x8*)(kb_g + (size_t)m0 * 64 + (t + 256) * 8);
    *(u16x8*)&vbuf[r0 * 72 + c0]        = *(const u16x8*)(vb_g + (size_t)r0 * NN + m0 + c0);
    *(u16x8*)&vbuf[(r0 + 32) * 72 + c0] = *(const u16x8*)(vb_g + (size_t)(r0 + 32) * NN + m0 + c0);
    __syncthreads();

    // S^T tiles: D[m_local][n] ; lane holds m = 16*mt + 4*q + r, n = ln
    f32x4 s[4];
#pragma unroll
    for (int mt = 0; mt < 4; mt++) {
      int krow = (16 * mt + ln) * 72;
      bhalf8 ka0 = *(const bhalf8*)&kbuf[krow + q * 8];
      bhalf8 ka1 = *(const bhalf8*)&kbuf[krow + 32 + q * 8];
      f32x4 acc = {0.f, 0.f, 0.f, 0.f};
      acc = MFMA16(ka0, qf0, acc);
      acc = MFMA16(ka1, qf1, acc);
      s[mt] = acc;
    }
    // online softmax (values are already in log2 domain scale)
    float tmax = s[0][0];
#pragma unroll
    for (int mt = 0; mt < 4; mt++)
#pragma unroll
      for (int r = 0; r < 4; r++) tmax = fmaxf(tmax, s[mt][r]);
    tmax = fmaxf(tmax, __shfl_xor(tmax, 16, 64));
    tmax = fmaxf(tmax, __shfl_xor(tmax, 32, 64));
    float m_new = fmaxf(m_i, tmax);
    float alpha = __builtin_amdgcn_exp2f(m_i - m_new);
    float tsum = 0.f;
#pragma unroll
    for (int mt = 0; mt < 4; mt++) {
      f32x4 p;
#pragma unroll
      for (int r = 0; r < 4; r++) { p[r] = __builtin_amdgcn_exp2f(s[mt][r] - m_new); tsum += p[r]; }
      u32x2 pk;
      pk[0] = (unsigned)f2bf(p[0]) | ((unsigned)f2bf(p[1]) << 16);
      pk[1] = (unsigned)f2bf(p[2]) | ((unsigned)f2bf(p[3]) << 16);
      *(u32x2*)&pb[ln * 72 + (4 * mt + q) * 4] = pk;  // m-block (4*mt+q), 4 consecutive m
    }
    tsum += __shfl_xor(tsum, 16, 64);
    tsum += __shfl_xor(tsum, 32, 64);
    l_i = l_i * alpha + tsum;
    m_i = m_new;
#pragma unroll
    for (int i = 0; i < 4; i++) o[i] *= alpha;
    // PV: O^T += V^T * P^T
#pragma unroll
    for (int s2 = 0; s2 < 2; s2++) {
      bhalf8 pf = *(const bhalf8*)&pb[ln * 72 + (8 * s2 + 2 * q) * 4];
#pragma unroll
      for (int ct = 0; ct < 4; ct++) {
        int vrow = (16 * ct + ln) * 72;
        bhalf8 va = *(const bhalf8*)&vbuf[vrow + 32 * s2 + q * 8];
        o[ct] = MFMA16(va, pf, o[ct]);
      }
    }
    __syncthreads();
  }
  float rl = 1.0f / l_i;
  int n = n0w + ln;
#pragma unroll
  for (int ct = 0; ct < 4; ct++) {
    f32x4 bv4 = *(const f32x4*)&bv[16 * ct + 4 * q];
    u16x4 pk;
#pragma unroll
    for (int r = 0; r < 4; r++) pk[r] = f2bf(o[ct][r] * rl + bv4[r]);
    *(u16x4*)&Ot[(size_t)(b * NN + n) * 64 + 16 * ct + 4 * q] = pk;
  }
}

// ---------------------------------------------------------------------------
// out: out = x + Wo*o + bo via MFMA (normal orientation), float4 stores.
// ---------------------------------------------------------------------------
extern "C" __global__ __launch_bounds__(256, 4) void out_kernel(
    const float* __restrict__ x, const u16* __restrict__ wob, const float* __restrict__ bo,
    const u16* __restrict__ Ot, float* __restrict__ out) {
  int b = blockIdx.x / NTILES, tile = blockIdx.x % NTILES;
  int t = threadIdx.x;
  int w = t >> 6, lane = t & 63, q = lane >> 4, ln = lane & 15;
  int n0w = tile * 64 + 16 * w;
  const u16* op = Ot + (size_t)(b * NN + n0w + ln) * 64 + q * 8;
  bhalf8 a0 = *(const bhalf8*)op;
  bhalf8 a1 = *(const bhalf8*)(op + 32);
#pragma unroll
  for (int ct = 0; ct < 4; ct++) {
    int wrow = (16 * ct + ln) * 64;
    bhalf8 b0 = *(const bhalf8*)&wob[wrow + q * 8];
    bhalf8 b1 = *(const bhalf8*)&wob[wrow + 32 + q * 8];
    f32x4 d = {0.f, 0.f, 0.f, 0.f};
    d = MFMA16(a0, b0, d);
    d = MFMA16(a1, b1, d);
    int co = 16 * ct + ln;
    size_t base = (size_t)(b * 64 + co) * NN + n0w + 4 * q;
    f32x4 xv = *(const f32x4*)&x[base];
    float bc = bo[co];
    f32x4 ov;
#pragma unroll
    for (int r = 0; r < 4; r++) ov[r] = xv[r] + bc + d[r];
    *(f32x4*)&out[base] = ov;
  }
}

extern "C" void kernel_launch(void* const* d_in, const int* in_sizes, int n_in,
                              void* d_out, int out_size, void* d_ws, size_t ws_size,
                              hipStream_t stream) {
  (void)in_sizes; (void)n_in; (void)out_size; (void)ws_size;
  const float* x  = (const float*)d_in[0];
  const float* wq = (const float*)d_in[1];
  const float* bq = (const float*)d_in[2];
  const float* wk = (const float*)d_in[3];
  const float* bk = (const float*)d_in[4];
  const float* wv = (const float*)d_in[5];
  const float* bv = (const float*)d_in[6];
  const float* wo = (const float*)d_in[7];
  const float* bo = (const float*)d_in[8];
  float* out = (float*)d_out;
  char* ws = (char*)d_ws;
  // workspace layout (all 16B aligned): ~18.9 MB total
  float* mean = (float*)ws;                 // 256 f32
  float* rstd = (float*)(ws + 1024);        // 256 f32
  u16* wbf = (u16*)(ws + 2048);             // 16384 bf16 (wq,wk,wv,wo)
  u16* Qt = (u16*)(ws + 36864);             // [B][N][64] bf16
  u16* Kt = Qt + (size_t)BB * NN * 64;      // [B][N][64] bf16
  u16* Vt = Kt + (size_t)BB * NN * 64;      // [B][64][N] bf16
  u16* Ot = Vt + (size_t)BB * NN * 64;      // [B][N][64] bf16
  const u16* wqb = wbf;
  const u16* wkb = wbf + 4096;
  const u16* wvb = wbf + 8192;
  const u16* wob = wbf + 12288;

  prep_kernel<<<320, 256, 0, stream>>>(x, wq, wk, wv, wo, mean, rstd, wbf);
  qkv_kernel<<<BB * NTILES, 256, 0, stream>>>(x, mean, rstd, wqb, wkb, wvb, bq, bk, Qt, Kt, Vt);
  flash_kernel<<<BB * NTILES, 256, 0, stream>>>(Qt, Kt, Vt, bv, Ot);
  out_kernel<<<BB * NTILES, 256, 0, stream>>>(x, wob, bo, Ot, out);
}

// Round 2
// 285.709 us; speedup vs baseline: 1.2510x; 1.2510x over previous
//
#include <hip/hip_runtime.h>
#include <stdint.h>

#define BB 4
#define CCH 64
#define NN 9216      // 96*96
#define NTILES 144   // NN/64  (qkv/out kernels: 64-wide n tiles)
#define FTILES 72    // NN/128 (flash: 128 Q-rows per block)
#define NCHUNK 4     // split-K chunks
#define CHUNKK 2304  // NN/NCHUNK keys per chunk

typedef unsigned short u16;
typedef __attribute__((ext_vector_type(8))) short bhalf8;   // 8 bf16 lanes of an MFMA operand
typedef __attribute__((ext_vector_type(4))) float f32x4;
typedef __attribute__((ext_vector_type(4))) u16 u16x4;
typedef __attribute__((ext_vector_type(8))) u16 u16x8;
typedef __attribute__((ext_vector_type(2))) unsigned int u32x2;

#define MFMA16(a, b, c) __builtin_amdgcn_mfma_f32_16x16x32_bf16((a), (b), (c), 0, 0, 0)

static __device__ __forceinline__ u16 f2bf(float f) {
  union { float f; unsigned u; } v; v.f = f;
  return (u16)((v.u + 0x7fffu + ((v.u >> 16) & 1u)) >> 16);  // RNE
}
static __device__ __forceinline__ float bf2f(u16 h) {
  union { unsigned u; float f; } v; v.u = ((unsigned)h) << 16; return v.f;
}

// ---------------------------------------------------------------------------
// prep: blocks [0,256): per-(b,c) mean/rstd over 9216 spatial elems.
//       blocks [256,320): convert wq,wk,wv,wo (4*4096 f32) to bf16.
// ---------------------------------------------------------------------------
extern "C" __global__ __launch_bounds__(256) void prep_kernel(
    const float* __restrict__ x,
    const float* __restrict__ wq, const float* __restrict__ wk,
    const float* __restrict__ wv, const float* __restrict__ wo,
    float* __restrict__ mean, float* __restrict__ rstd, u16* __restrict__ wbf) {
  if (blockIdx.x >= 256) {
    int i = (blockIdx.x - 256) * 256 + threadIdx.x;  // 0..16383
    const float* src = (i < 4096) ? wq : (i < 8192) ? wk : (i < 12288) ? wv : wo;
    wbf[i] = f2bf(src[i & 4095]);
    return;
  }
  int idx = blockIdx.x;
  const float* p = x + (size_t)idx * NN;
  float s = 0.f, ss = 0.f;
  for (int i = threadIdx.x; i < NN; i += 256) { float v = p[i]; s += v; ss += v * v; }
#pragma unroll
  for (int o = 32; o > 0; o >>= 1) { s += __shfl_xor(s, o, 64); ss += __shfl_xor(ss, o, 64); }
  __shared__ float ls[4], lss[4];
  int w = threadIdx.x >> 6;
  if ((threadIdx.x & 63) == 0) { ls[w] = s; lss[w] = ss; }
  __syncthreads();
  if (threadIdx.x == 0) {
    s = ls[0] + ls[1] + ls[2] + ls[3];
    ss = lss[0] + lss[1] + lss[2] + lss[3];
    float m = s * (1.f / NN);
    float var = ss * (1.f / NN) - m * m;
    mean[idx] = m;
    rstd[idx] = rsqrtf(var + 1e-5f);
  }
}

// ---------------------------------------------------------------------------
// qkv: fused instance-norm + 1x1 convs via MFMA.
// Qt,Kt = [B][N][64] bf16 (Q pre-scaled by 0.125*log2e), Vt = [B][64][N] bf16.
// ---------------------------------------------------------------------------
extern "C" __global__ __launch_bounds__(256, 4) void qkv_kernel(
    const float* __restrict__ x,
    const float* __restrict__ mean, const float* __restrict__ rstd,
    const u16* __restrict__ wqb, const u16* __restrict__ wkb, const u16* __restrict__ wvb,
    const float* __restrict__ bq, const float* __restrict__ bk,
    u16* __restrict__ Qt, u16* __restrict__ Kt, u16* __restrict__ Vt) {
  __shared__ u16 hbuf[64 * 72];  // [n_local][c], padded rows
  int b = blockIdx.x / NTILES, tile = blockIdx.x % NTILES;
  int n0 = tile * 64;
  int t = threadIdx.x;
  int w = t >> 6, lane = t & 63, q = lane >> 4, ln = lane & 15;
  const float QSCALE = 0.125f * 1.44269504088896340736f;  // C^-0.5 * log2(e)
#pragma unroll
  for (int rep = 0; rep < 16; rep++) {
    int c = rep * 4 + w;
    float v = x[(size_t)(b * 64 + c) * NN + n0 + lane];
    float h = (v - mean[b * 64 + c]) * rstd[b * 64 + c];
    hbuf[lane * 72 + c] = f2bf(h);
  }
  __syncthreads();
  int hrow = (16 * w + ln) * 72;
  bhalf8 hb0 = *(const bhalf8*)&hbuf[hrow + q * 8];
  bhalf8 hb1 = *(const bhalf8*)&hbuf[hrow + 32 + q * 8];
  size_t nrow = (size_t)(b * NN + n0 + 16 * w + ln) * 64;
  // ---- Q (transposed orientation: reg quad = 4 consecutive channels) ----
#pragma unroll
  for (int ct = 0; ct < 4; ct++) {
    int wrow = (16 * ct + ln) * 64;
    bhalf8 a0 = *(const bhalf8*)&wqb[wrow + q * 8];
    bhalf8 a1 = *(const bhalf8*)&wqb[wrow + 32 + q * 8];
    f32x4 d = {0.f, 0.f, 0.f, 0.f};
    d = MFMA16(a0, hb0, d);
    d = MFMA16(a1, hb1, d);
    f32x4 b4 = *(const f32x4*)&bq[16 * ct + 4 * q];
    u16x4 pk;
#pragma unroll
    for (int r = 0; r < 4; r++) pk[r] = f2bf((d[r] + b4[r]) * QSCALE);
    *(u16x4*)&Qt[nrow + 16 * ct + 4 * q] = pk;
  }
  // ---- K ----
#pragma unroll
  for (int ct = 0; ct < 4; ct++) {
    int wrow = (16 * ct + ln) * 64;
    bhalf8 a0 = *(const bhalf8*)&wkb[wrow + q * 8];
    bhalf8 a1 = *(const bhalf8*)&wkb[wrow + 32 + q * 8];
    f32x4 d = {0.f, 0.f, 0.f, 0.f};
    d = MFMA16(a0, hb0, d);
    d = MFMA16(a1, hb1, d);
    f32x4 b4 = *(const f32x4*)&bk[16 * ct + 4 * q];
    u16x4 pk;
#pragma unroll
    for (int r = 0; r < 4; r++) pk[r] = f2bf(d[r] + b4[r]);
    *(u16x4*)&Kt[nrow + 16 * ct + 4 * q] = pk;
  }
  // ---- V (normal orientation; bv folded into merge) ----
#pragma unroll
  for (int ct = 0; ct < 4; ct++) {
    int wrow = (16 * ct + ln) * 64;
    bhalf8 b0 = *(const bhalf8*)&wvb[wrow + q * 8];
    bhalf8 b1 = *(const bhalf8*)&wvb[wrow + 32 + q * 8];
    f32x4 d = {0.f, 0.f, 0.f, 0.f};
    d = MFMA16(hb0, b0, d);
    d = MFMA16(hb1, b1, d);
    u16x4 pk;
#pragma unroll
    for (int r = 0; r < 4; r++) pk[r] = f2bf(d[r]);
    *(u16x4*)&Vt[(size_t)(b * 64 + 16 * ct + ln) * NN + n0 + 16 * w + 4 * q] = pk;
  }
}

// ---------------------------------------------------------------------------
// flash: split-K online-softmax attention.
// Block = 4 waves x 32 Q-rows = 128 rows; one of 4 key-chunks (2304 keys).
// S^T orientation (A=K): softmax over keys is in-lane + 2 shuffles.
// Emits unnormalized partial O (bf16) + per-row (m,l).
// ---------------------------------------------------------------------------
extern "C" __global__ __launch_bounds__(256, 4) void flash_kernel(
    const u16* __restrict__ Qt, const u16* __restrict__ Kt, const u16* __restrict__ Vt,
    u16* __restrict__ Opart, float* __restrict__ Ml) {
  __shared__ u16 kbuf[64 * 72];        // [m_local][c]
  __shared__ u16 vbuf[64 * 72];        // [c][m_local]
  __shared__ u16 pbuf[4 * 32 * 72];    // per-wave [n_local(32)][m]
  int blk = blockIdx.x;
  int b = blk / (FTILES * NCHUNK);
  int rem = blk % (FTILES * NCHUNK);
  int tile = rem >> 2, chunk = rem & 3;
  int m_start = chunk * CHUNKK;
  int t = threadIdx.x;
  int w = t >> 6, lane = t & 63, q = lane >> 4, ln = lane & 15;
  int n0w = tile * 128 + 32 * w;
  // Q fragments for 32 rows: set a = rows [n0w, n0w+16), set b = +16
  const u16* qp = Qt + (size_t)(b * NN + n0w + ln) * 64 + q * 8;
  bhalf8 qa0 = *(const bhalf8*)qp;
  bhalf8 qa1 = *(const bhalf8*)(qp + 32);
  bhalf8 qb0 = *(const bhalf8*)(qp + 16 * 64);
  bhalf8 qb1 = *(const bhalf8*)(qp + 16 * 64 + 32);
  f32x4 oa[4], ob[4];
#pragma unroll
  for (int i = 0; i < 4; i++) { oa[i] = (f32x4){0.f,0.f,0.f,0.f}; ob[i] = (f32x4){0.f,0.f,0.f,0.f}; }
  float ma = -3.0e38f, la = 0.f, mb = -3.0e38f, lb = 0.f;
  u16* pb = pbuf + w * (32 * 72);
  const u16* kb_g = Kt + ((size_t)b * NN + m_start) * 64;
  const u16* vb_g = Vt + (size_t)b * 64 * NN + m_start;
  int r0 = t >> 3, c0 = (t & 7) * 8;

  for (int m0 = 0; m0 < CHUNKK; m0 += 64) {
    *(u16x8*)&kbuf[r0 * 72 + c0]        = *(const u16x8*)(kb_g + (size_t)m0 * 64 + t * 8);
    *(u16x8*)&kbuf[(r0 + 32) * 72 + c0] = *(const u16x8*)(kb_g + (size_t)m0 * 64 + (t + 256) * 8);
    *(u16x8*)&vbuf[r0 * 72 + c0]        = *(const u16x8*)(vb_g + (size_t)r0 * NN + m0 + c0);
    *(u16x8*)&vbuf[(r0 + 32) * 72 + c0] = *(const u16x8*)(vb_g + (size_t)(r0 + 32) * NN + m0 + c0);
    __syncthreads();

    // S^T: lane holds m = 16*mt + 4*q + r ; n = ln (set a) / ln+16 (set b)
    f32x4 sa[4], sb[4];
#pragma unroll
    for (int mt = 0; mt < 4; mt++) {
      int krow = (16 * mt + ln) * 72;
      bhalf8 ka0 = *(const bhalf8*)&kbuf[krow + q * 8];
      bhalf8 ka1 = *(const bhalf8*)&kbuf[krow + 32 + q * 8];
      f32x4 acc = {0.f, 0.f, 0.f, 0.f};
      acc = MFMA16(ka0, qa0, acc);
      acc = MFMA16(ka1, qa1, acc);
      sa[mt] = acc;
      f32x4 acc2 = {0.f, 0.f, 0.f, 0.f};
      acc2 = MFMA16(ka0, qb0, acc2);
      acc2 = MFMA16(ka1, qb1, acc2);
      sb[mt] = acc2;
    }
    // online softmax (scores already in log2 domain)
    float ta = sa[0][0], tb = sb[0][0];
#pragma unroll
    for (int mt = 0; mt < 4; mt++)
#pragma unroll
      for (int r = 0; r < 4; r++) { ta = fmaxf(ta, sa[mt][r]); tb = fmaxf(tb, sb[mt][r]); }
    ta = fmaxf(ta, __shfl_xor(ta, 16, 64)); ta = fmaxf(ta, __shfl_xor(ta, 32, 64));
    tb = fmaxf(tb, __shfl_xor(tb, 16, 64)); tb = fmaxf(tb, __shfl_xor(tb, 32, 64));
    float mna = fmaxf(ma, ta), mnb = fmaxf(mb, tb);
    float aa = __builtin_amdgcn_exp2f(ma - mna);
    float ab = __builtin_amdgcn_exp2f(mb - mnb);
    float tsa = 0.f, tsb = 0.f;
#pragma unroll
    for (int mt = 0; mt < 4; mt++) {
      f32x4 pa, pbv;
#pragma unroll
      for (int r = 0; r < 4; r++) {
        pa[r] = __builtin_amdgcn_exp2f(sa[mt][r] - mna); tsa += pa[r];
        pbv[r] = __builtin_amdgcn_exp2f(sb[mt][r] - mnb); tsb += pbv[r];
      }
      u32x2 pk;
      pk[0] = (unsigned)f2bf(pa[0]) | ((unsigned)f2bf(pa[1]) << 16);
      pk[1] = (unsigned)f2bf(pa[2]) | ((unsigned)f2bf(pa[3]) << 16);
      *(u32x2*)&pb[ln * 72 + (4 * mt + q) * 4] = pk;
      pk[0] = (unsigned)f2bf(pbv[0]) | ((unsigned)f2bf(pbv[1]) << 16);
      pk[1] = (unsigned)f2bf(pbv[2]) | ((unsigned)f2bf(pbv[3]) << 16);
      *(u32x2*)&pb[(16 + ln) * 72 + (4 * mt + q) * 4] = pk;
    }
    tsa += __shfl_xor(tsa, 16, 64); tsa += __shfl_xor(tsa, 32, 64);
    tsb += __shfl_xor(tsb, 16, 64); tsb += __shfl_xor(tsb, 32, 64);
    la = la * aa + tsa; ma = mna;
    lb = lb * ab + tsb; mb = mnb;
#pragma unroll
    for (int i = 0; i < 4; i++) { oa[i] *= aa; ob[i] *= ab; }
    // PV: O^T += V^T * P^T  (va shared between both row-sets)
#pragma unroll
    for (int s2 = 0; s2 < 2; s2++) {
      bhalf8 pfa = *(const bhalf8*)&pb[ln * 72 + (8 * s2 + 2 * q) * 4];
      bhalf8 pfb = *(const bhalf8*)&pb[(16 + ln) * 72 + (8 * s2 + 2 * q) * 4];
#pragma unroll
      for (int ct = 0; ct < 4; ct++) {
        int vrow = (16 * ct + ln) * 72;
        bhalf8 va = *(const bhalf8*)&vbuf[vrow + 32 * s2 + q * 8];
        oa[ct] = MFMA16(va, pfa, oa[ct]);
        ob[ct] = MFMA16(va, pfb, ob[ct]);
      }
    }
    __syncthreads();
  }
  // emit partial (unnormalized O in bf16, m/l per row)
  size_t pbase = (size_t)blk * (128 * 64);
  int ra = 32 * w + ln, rb = ra + 16;
#pragma unroll
  for (int ct = 0; ct < 4; ct++) {
    u16x4 pka, pkb;
#pragma unroll
    for (int r = 0; r < 4; r++) { pka[r] = f2bf(oa[ct][r]); pkb[r] = f2bf(ob[ct][r]); }
    *(u16x4*)&Opart[pbase + (size_t)ra * 64 + 16 * ct + 4 * q] = pka;
    *(u16x4*)&Opart[pbase + (size_t)rb * 64 + 16 * ct + 4 * q] = pkb;
  }
  if (q == 0) {
    float* mlb = Ml + (size_t)blk * 256;
    mlb[ra * 2] = ma; mlb[ra * 2 + 1] = la;
    mlb[rb * 2] = mb; mlb[rb * 2 + 1] = lb;
  }
}

// ---------------------------------------------------------------------------
// merge: combine 4 split-K partials -> Ot = [B][N][64] bf16 (adds bv, /l).
// grid 288 blocks x 256 thr; thread = (row, 32-col half).
// ---------------------------------------------------------------------------
extern "C" __global__ __launch_bounds__(256) void merge_kernel(
    const u16* __restrict__ Opart, const float* __restrict__ Ml,
    const float* __restrict__ bv, u16* __restrict__ Ot) {
  int b = blockIdx.x / FTILES, tile = blockIdx.x % FTILES;
  int t = threadIdx.x;
  int row = t >> 1, half = t & 1, c0 = 32 * half;
  int p0 = (b * FTILES + tile) * NCHUNK;
  float mc[4], lc[4];
#pragma unroll
  for (int ch = 0; ch < 4; ch++) {
    const float* mlb = Ml + (size_t)(p0 + ch) * 256 + row * 2;
    mc[ch] = mlb[0]; lc[ch] = mlb[1];
  }
  float mstar = fmaxf(fmaxf(mc[0], mc[1]), fmaxf(mc[2], mc[3]));
  float wch[4], L = 0.f;
#pragma unroll
  for (int ch = 0; ch < 4; ch++) { wch[ch] = __builtin_amdgcn_exp2f(mc[ch] - mstar); L += wch[ch] * lc[ch]; }
  float rl = 1.0f / L;
  float acc[32];
#pragma unroll
  for (int j = 0; j < 32; j++) acc[j] = 0.f;
#pragma unroll
  for (int ch = 0; ch < 4; ch++) {
    const u16* op = Opart + ((size_t)(p0 + ch) * 128 + row) * 64 + c0;
    float wc = wch[ch];
#pragma unroll
    for (int v = 0; v < 4; v++) {
      u16x8 d = *(const u16x8*)(op + v * 8);
#pragma unroll
      for (int j = 0; j < 8; j++) acc[v * 8 + j] += wc * bf2f(d[j]);
    }
  }
  u16* dst = Ot + (size_t)(b * NN + tile * 128 + row) * 64 + c0;
#pragma unroll
  for (int v = 0; v < 4; v++) {
    u16x8 pk;
#pragma unroll
    for (int j = 0; j < 8; j++) pk[j] = f2bf(acc[v * 8 + j] * rl + bv[c0 + v * 8 + j]);
    *(u16x8*)(dst + v * 8) = pk;
  }
}

// ---------------------------------------------------------------------------
// out: out = x + Wo*o + bo via MFMA, float4 stores.
// ---------------------------------------------------------------------------
extern "C" __global__ __launch_bounds__(256, 4) void out_kernel(
    const float* __restrict__ x, const u16* __restrict__ wob, const float* __restrict__ bo,
    const u16* __restrict__ Ot, float* __restrict__ out) {
  int b = blockIdx.x / NTILES, tile = blockIdx.x % NTILES;
  int t = threadIdx.x;
  int w = t >> 6, lane = t & 63, q = lane >> 4, ln = lane & 15;
  int n0w = tile * 64 + 16 * w;
  const u16* op = Ot + (size_t)(b * NN + n0w + ln) * 64 + q * 8;
  bhalf8 a0 = *(const bhalf8*)op;
  bhalf8 a1 = *(const bhalf8*)(op + 32);
#pragma unroll
  for (int ct = 0; ct < 4; ct++) {
    int wrow = (16 * ct + ln) * 64;
    bhalf8 b0 = *(const bhalf8*)&wob[wrow + q * 8];
    bhalf8 b1 = *(const bhalf8*)&wob[wrow + 32 + q * 8];
    f32x4 d = {0.f, 0.f, 0.f, 0.f};
    d = MFMA16(a0, b0, d);
    d = MFMA16(a1, b1, d);
    int co = 16 * ct + ln;
    size_t base = (size_t)(b * 64 + co) * NN + n0w + 4 * q;
    f32x4 xv = *(const f32x4*)&x[base];
    float bc = bo[co];
    f32x4 ov;
#pragma unroll
    for (int r = 0; r < 4; r++) ov[r] = xv[r] + bc + d[r];
    *(f32x4*)&out[base] = ov;
  }
}

extern "C" void kernel_launch(void* const* d_in, const int* in_sizes, int n_in,
                              void* d_out, int out_size, void* d_ws, size_t ws_size,
                              hipStream_t stream) {
  (void)in_sizes; (void)n_in; (void)out_size; (void)ws_size;
  const float* x  = (const float*)d_in[0];
  const float* wq = (const float*)d_in[1];
  const float* bq = (const float*)d_in[2];
  const float* wk = (const float*)d_in[3];
  const float* bk = (const float*)d_in[4];
  const float* wv = (const float*)d_in[5];
  const float* bv = (const float*)d_in[6];
  const float* wo = (const float*)d_in[7];
  const float* bo = (const float*)d_in[8];
  float* out = (float*)d_out;
  char* ws = (char*)d_ws;
  // workspace layout (16B aligned), ~39.2 MB total
  float* mean = (float*)ws;                   // 256 f32
  float* rstd = (float*)(ws + 1024);          // 256 f32
  u16* wbf = (u16*)(ws + 2048);               // 16384 bf16
  u16* Qt = (u16*)(ws + 36864);               // [B][N][64] bf16  4.72MB
  u16* Kt = Qt + (size_t)BB * NN * 64;
  u16* Vt = Kt + (size_t)BB * NN * 64;
  u16* Ot = Vt + (size_t)BB * NN * 64;
  u16* Opart = Ot + (size_t)BB * NN * 64;     // 1152 * 128*64 bf16 = 18.9MB
  float* Ml = (float*)(Opart + (size_t)BB * FTILES * NCHUNK * 128 * 64);  // 1152*256 f32 = 1.18MB
  const u16* wqb = wbf;
  const u16* wkb = wbf + 4096;
  const u16* wvb = wbf + 8192;
  const u16* wob = wbf + 12288;

  prep_kernel<<<320, 256, 0, stream>>>(x, wq, wk, wv, wo, mean, rstd, wbf);
  qkv_kernel<<<BB * NTILES, 256, 0, stream>>>(x, mean, rstd, wqb, wkb, wvb, bq, bk, Qt, Kt, Vt);
  flash_kernel<<<BB * FTILES * NCHUNK, 256, 0, stream>>>(Qt, Kt, Vt, Opart, Ml);
  merge_kernel<<<BB * FTILES, 256, 0, stream>>>(Opart, Ml, bv, Ot);
  out_kernel<<<BB * NTILES, 256, 0, stream>>>(x, wob, bo, Ot, out);
}

// Round 3
// 260.437 us; speedup vs baseline: 1.3723x; 1.0970x over previous
//
#include <hip/hip_runtime.h>
#include <stdint.h>

#define BB 4
#define CCH 64
#define NN 9216      // 96*96
#define NTILES 144   // NN/64  (qkv/out kernels: 64-wide n tiles)
#define FTILES 72    // NN/128 (flash: 128 Q-rows per block)
#define NCHUNK 4     // split-K chunks
#define CHUNKK 2304  // NN/NCHUNK keys per chunk

typedef unsigned short u16;
typedef __attribute__((ext_vector_type(8))) short bhalf8;   // 8 bf16 lanes of an MFMA operand
typedef __attribute__((ext_vector_type(4))) float f32x4;
typedef __attribute__((ext_vector_type(4))) u16 u16x4;
typedef __attribute__((ext_vector_type(8))) u16 u16x8;
typedef __attribute__((ext_vector_type(2))) unsigned int u32x2;

#define MFMA16(a, b, c) __builtin_amdgcn_mfma_f32_16x16x32_bf16((a), (b), (c), 0, 0, 0)

static __device__ __forceinline__ u16 f2bf(float f) {
  union { float f; unsigned u; } v; v.f = f;
  return (u16)((v.u + 0x7fffu + ((v.u >> 16) & 1u)) >> 16);  // RNE
}
static __device__ __forceinline__ float bf2f(u16 h) {
  union { unsigned u; float f; } v; v.u = ((unsigned)h) << 16; return v.f;
}
// pack two f32 -> (bf16(hi)<<16)|bf16(lo), round-half-up, 3 VALU ops total
static __device__ __forceinline__ unsigned pk2(float lo, float hi) {
  unsigned a = __float_as_uint(hi) + 0x8000u;
  unsigned b = __float_as_uint(lo) + 0x8000u;
  return __builtin_amdgcn_perm(a, b, 0x07060302u);  // bytes {a3,a2,b3,b2}
}
// async global->LDS, 16B per lane; lds dest = wave-uniform base + lane*16
static __device__ __forceinline__ void glds16(const void* g, void* l) {
  __builtin_amdgcn_global_load_lds(
      (const __attribute__((address_space(1))) unsigned int*)g,
      (__attribute__((address_space(3))) unsigned int*)l, 16, 0, 0);
}

// ---------------------------------------------------------------------------
// prep: blocks [0,256): per-(b,c) mean/rstd over 9216 spatial elems.
//       blocks [256,320): convert wq,wk,wv,wo (4*4096 f32) to bf16.
// ---------------------------------------------------------------------------
extern "C" __global__ __launch_bounds__(256) void prep_kernel(
    const float* __restrict__ x,
    const float* __restrict__ wq, const float* __restrict__ wk,
    const float* __restrict__ wv, const float* __restrict__ wo,
    float* __restrict__ mean, float* __restrict__ rstd, u16* __restrict__ wbf) {
  if (blockIdx.x >= 256) {
    int i = (blockIdx.x - 256) * 256 + threadIdx.x;  // 0..16383
    const float* src = (i < 4096) ? wq : (i < 8192) ? wk : (i < 12288) ? wv : wo;
    wbf[i] = f2bf(src[i & 4095]);
    return;
  }
  int idx = blockIdx.x;
  const float* p = x + (size_t)idx * NN;
  float s = 0.f, ss = 0.f;
  for (int i = threadIdx.x; i < NN; i += 256) { float v = p[i]; s += v; ss += v * v; }
#pragma unroll
  for (int o = 32; o > 0; o >>= 1) { s += __shfl_xor(s, o, 64); ss += __shfl_xor(ss, o, 64); }
  __shared__ float ls[4], lss[4];
  int w = threadIdx.x >> 6;
  if ((threadIdx.x & 63) == 0) { ls[w] = s; lss[w] = ss; }
  __syncthreads();
  if (threadIdx.x == 0) {
    s = ls[0] + ls[1] + ls[2] + ls[3];
    ss = lss[0] + lss[1] + lss[2] + lss[3];
    float m = s * (1.f / NN);
    float var = ss * (1.f / NN) - m * m;
    mean[idx] = m;
    rstd[idx] = rsqrtf(var + 1e-5f);
  }
}

// ---------------------------------------------------------------------------
// qkv: fused instance-norm + 1x1 convs via MFMA.
// Qt,Kt = [B][N][64] bf16 (Q pre-scaled by 0.125*log2e), Vt = [B][64][N] bf16.
// ---------------------------------------------------------------------------
extern "C" __global__ __launch_bounds__(256, 4) void qkv_kernel(
    const float* __restrict__ x,
    const float* __restrict__ mean, const float* __restrict__ rstd,
    const u16* __restrict__ wqb, const u16* __restrict__ wkb, const u16* __restrict__ wvb,
    const float* __restrict__ bq, const float* __restrict__ bk,
    u16* __restrict__ Qt, u16* __restrict__ Kt, u16* __restrict__ Vt) {
  __shared__ u16 hbuf[64 * 72];  // [n_local][c], padded rows
  int b = blockIdx.x / NTILES, tile = blockIdx.x % NTILES;
  int n0 = tile * 64;
  int t = threadIdx.x;
  int w = t >> 6, lane = t & 63, q = lane >> 4, ln = lane & 15;
  const float QSCALE = 0.125f * 1.44269504088896340736f;  // C^-0.5 * log2(e)
#pragma unroll
  for (int rep = 0; rep < 16; rep++) {
    int c = rep * 4 + w;
    float v = x[(size_t)(b * 64 + c) * NN + n0 + lane];
    float h = (v - mean[b * 64 + c]) * rstd[b * 64 + c];
    hbuf[lane * 72 + c] = f2bf(h);
  }
  __syncthreads();
  int hrow = (16 * w + ln) * 72;
  bhalf8 hb0 = *(const bhalf8*)&hbuf[hrow + q * 8];
  bhalf8 hb1 = *(const bhalf8*)&hbuf[hrow + 32 + q * 8];
  size_t nrow = (size_t)(b * NN + n0 + 16 * w + ln) * 64;
  // ---- Q (transposed orientation: reg quad = 4 consecutive channels) ----
#pragma unroll
  for (int ct = 0; ct < 4; ct++) {
    int wrow = (16 * ct + ln) * 64;
    bhalf8 a0 = *(const bhalf8*)&wqb[wrow + q * 8];
    bhalf8 a1 = *(const bhalf8*)&wqb[wrow + 32 + q * 8];
    f32x4 d = {0.f, 0.f, 0.f, 0.f};
    d = MFMA16(a0, hb0, d);
    d = MFMA16(a1, hb1, d);
    f32x4 b4 = *(const f32x4*)&bq[16 * ct + 4 * q];
    u16x4 pk;
#pragma unroll
    for (int r = 0; r < 4; r++) pk[r] = f2bf((d[r] + b4[r]) * QSCALE);
    *(u16x4*)&Qt[nrow + 16 * ct + 4 * q] = pk;
  }
  // ---- K ----
#pragma unroll
  for (int ct = 0; ct < 4; ct++) {
    int wrow = (16 * ct + ln) * 64;
    bhalf8 a0 = *(const bhalf8*)&wkb[wrow + q * 8];
    bhalf8 a1 = *(const bhalf8*)&wkb[wrow + 32 + q * 8];
    f32x4 d = {0.f, 0.f, 0.f, 0.f};
    d = MFMA16(a0, hb0, d);
    d = MFMA16(a1, hb1, d);
    f32x4 b4 = *(const f32x4*)&bk[16 * ct + 4 * q];
    u16x4 pk;
#pragma unroll
    for (int r = 0; r < 4; r++) pk[r] = f2bf(d[r] + b4[r]);
    *(u16x4*)&Kt[nrow + 16 * ct + 4 * q] = pk;
  }
  // ---- V (normal orientation; bv folded into merge) ----
#pragma unroll
  for (int ct = 0; ct < 4; ct++) {
    int wrow = (16 * ct + ln) * 64;
    bhalf8 b0 = *(const bhalf8*)&wvb[wrow + q * 8];
    bhalf8 b1 = *(const bhalf8*)&wvb[wrow + 32 + q * 8];
    f32x4 d = {0.f, 0.f, 0.f, 0.f};
    d = MFMA16(hb0, b0, d);
    d = MFMA16(hb1, b1, d);
    u16x4 pk;
#pragma unroll
    for (int r = 0; r < 4; r++) pk[r] = f2bf(d[r]);
    *(u16x4*)&Vt[(size_t)(b * 64 + 16 * ct + ln) * NN + n0 + 16 * w + 4 * q] = pk;
  }
}

// ---------------------------------------------------------------------------
// flash: split-K online-softmax attention.
// Block = 4 waves x 32 Q-rows = 128 rows; one of 4 key-chunks (2304 keys).
// K/V tiles staged via global_load_lds into XOR-swizzled unpadded LDS
// (swizzle lives in the per-lane global source address; Kt/Vt layout plain).
// S^T orientation (A=K): softmax over keys is in-lane + 2 shuffles.
// Emits unnormalized partial O (bf16) + per-row (m,l).
// ---------------------------------------------------------------------------
extern "C" __global__ __launch_bounds__(256, 4) void flash_kernel(
    const u16* __restrict__ Qt, const u16* __restrict__ Kt, const u16* __restrict__ Vt,
    u16* __restrict__ Opart, float* __restrict__ Ml) {
  __shared__ u16 kbuf[64 * 64];        // [m_local][c], 16B units swizzled by (row&7)
  __shared__ u16 vbuf[64 * 64];        // [c][m_local], 16B units swizzled by (row&7)
  __shared__ u16 pbuf[4 * 32 * 64];    // per-wave [n_local(32)][m], swizzled
  int blk = blockIdx.x;
  int b = blk / (FTILES * NCHUNK);
  int rem = blk % (FTILES * NCHUNK);
  int tile = rem >> 2, chunk = rem & 3;
  int m_start = chunk * CHUNKK;
  int t = threadIdx.x;
  int w = t >> 6, lane = t & 63, q = lane >> 4, ln = lane & 15;
  int n0w = tile * 128 + 32 * w;
  // Q fragments for 32 rows: set a = rows [n0w, n0w+16), set b = +16
  const u16* qp = Qt + (size_t)(b * NN + n0w + ln) * 64 + q * 8;
  bhalf8 qa0 = *(const bhalf8*)qp;
  bhalf8 qa1 = *(const bhalf8*)(qp + 32);
  bhalf8 qb0 = *(const bhalf8*)(qp + 16 * 64);
  bhalf8 qb1 = *(const bhalf8*)(qp + 16 * 64 + 32);
  f32x4 oa[4], ob[4];
#pragma unroll
  for (int i = 0; i < 4; i++) { oa[i] = (f32x4){0.f,0.f,0.f,0.f}; ob[i] = (f32x4){0.f,0.f,0.f,0.f}; }
  float ma = -3.0e38f, la = 0.f, mb = -3.0e38f, lb = 0.f;
  u16* pb = pbuf + w * 2048;           // 32 rows * 64 per wave
  // staging: wave w fills LDS rows [16w,16w+16); lane covers (row 16w+(lane>>3), unit lane&7)
  int row_s = 16 * w + (lane >> 3);
  int usw = (lane & 7) ^ (row_s & 7);  // swizzled global 16B-chunk index
  const u16* kgp = Kt + ((size_t)b * NN + m_start + row_s) * 64 + usw * 8;
  const u16* vgp = Vt + (size_t)(b * 64 + row_s) * NN + m_start + usw * 8;
  u16* klds = &kbuf[w * 1024];
  u16* vlds = &vbuf[w * 1024];
  int sbase = (q ^ (ln & 7)) * 8;      // swizzled chunk offset for fragment reads

  for (int m0 = 0; m0 < CHUNKK; m0 += 64) {
    __syncthreads();                   // all waves done reading previous tile
    glds16(kgp, klds);
    glds16(kgp + 512, klds + 512);     // rows +8 (same swizzle: (r+8)&7 == r&7)
    glds16(vgp, vlds);
    glds16(vgp + (size_t)8 * NN, vlds + 512);
    kgp += 64 * 64;
    vgp += 64;
    __syncthreads();                   // staged data visible (vmcnt drained before barrier)

    // S^T: lane holds m = 16*mt + 4*q + r ; n = ln (set a) / ln+16 (set b)
    f32x4 sa[4], sb[4];
#pragma unroll
    for (int mt = 0; mt < 4; mt++) {
      int krow = (16 * mt + ln) * 64;
      bhalf8 ka0 = *(const bhalf8*)&kbuf[krow + sbase];
      bhalf8 ka1 = *(const bhalf8*)&kbuf[krow + (sbase ^ 32)];
      f32x4 acc = {0.f, 0.f, 0.f, 0.f};
      acc = MFMA16(ka0, qa0, acc);
      acc = MFMA16(ka1, qa1, acc);
      sa[mt] = acc;
      f32x4 acc2 = {0.f, 0.f, 0.f, 0.f};
      acc2 = MFMA16(ka0, qb0, acc2);
      acc2 = MFMA16(ka1, qb1, acc2);
      sb[mt] = acc2;
    }
    // online softmax (scores already in log2 domain)
    float ta = sa[0][0], tb = sb[0][0];
#pragma unroll
    for (int mt = 0; mt < 4; mt++)
#pragma unroll
      for (int r = 0; r < 4; r++) { ta = fmaxf(ta, sa[mt][r]); tb = fmaxf(tb, sb[mt][r]); }
    ta = fmaxf(ta, __shfl_xor(ta, 16, 64)); ta = fmaxf(ta, __shfl_xor(ta, 32, 64));
    tb = fmaxf(tb, __shfl_xor(tb, 16, 64)); tb = fmaxf(tb, __shfl_xor(tb, 32, 64));
    float mna = fmaxf(ma, ta), mnb = fmaxf(mb, tb);
    if (__any((mna > ma) || (mnb > mb))) {   // wave-uniform: skip rescale when maxes unchanged
      float aa = __builtin_amdgcn_exp2f(ma - mna);
      float ab = __builtin_amdgcn_exp2f(mb - mnb);
      la *= aa; lb *= ab;
#pragma unroll
      for (int i = 0; i < 4; i++) { oa[i] *= aa; ob[i] *= ab; }
    }
    ma = mna; mb = mnb;
    float tsa = 0.f, tsb = 0.f;
#pragma unroll
    for (int mt = 0; mt < 4; mt++) {
      f32x4 pa, pbv;
#pragma unroll
      for (int r = 0; r < 4; r++) {
        pa[r] = __builtin_amdgcn_exp2f(sa[mt][r] - mna); tsa += pa[r];
        pbv[r] = __builtin_amdgcn_exp2f(sb[mt][r] - mnb); tsb += pbv[r];
      }
      int pu = (((2 * mt + (q >> 1)) ^ (ln & 7)) << 3) + ((q & 1) << 2);  // swizzled unit + 8B sub
      u32x2 pk;
      pk[0] = pk2(pa[0], pa[1]);
      pk[1] = pk2(pa[2], pa[3]);
      *(u32x2*)&pb[ln * 64 + pu] = pk;
      pk[0] = pk2(pbv[0], pbv[1]);
      pk[1] = pk2(pbv[2], pbv[3]);
      *(u32x2*)&pb[(16 + ln) * 64 + pu] = pk;
    }
    tsa += __shfl_xor(tsa, 16, 64); tsa += __shfl_xor(tsa, 32, 64);
    tsb += __shfl_xor(tsb, 16, 64); tsb += __shfl_xor(tsb, 32, 64);
    la += tsa; lb += tsb;
    // PV: O^T += V^T * P^T  (va shared between both row-sets)
#pragma unroll
    for (int s2 = 0; s2 < 2; s2++) {
      bhalf8 pfa = *(const bhalf8*)&pb[ln * 64 + (sbase ^ (32 * s2))];
      bhalf8 pfb = *(const bhalf8*)&pb[(16 + ln) * 64 + (sbase ^ (32 * s2))];
#pragma unroll
      for (int ct = 0; ct < 4; ct++) {
        int vrow = (16 * ct + ln) * 64;
        bhalf8 va = *(const bhalf8*)&vbuf[vrow + (sbase ^ (32 * s2))];
        oa[ct] = MFMA16(va, pfa, oa[ct]);
        ob[ct] = MFMA16(va, pfb, ob[ct]);
      }
    }
  }
  // emit partial (unnormalized O in bf16, m/l per row)
  size_t pbase = (size_t)blk * (128 * 64);
  int ra = 32 * w + ln, rb = ra + 16;
#pragma unroll
  for (int ct = 0; ct < 4; ct++) {
    u32x2 pka, pkb;
    pka[0] = pk2(oa[ct][0], oa[ct][1]); pka[1] = pk2(oa[ct][2], oa[ct][3]);
    pkb[0] = pk2(ob[ct][0], ob[ct][1]); pkb[1] = pk2(ob[ct][2], ob[ct][3]);
    *(u32x2*)&Opart[pbase + (size_t)ra * 64 + 16 * ct + 4 * q] = pka;
    *(u32x2*)&Opart[pbase + (size_t)rb * 64 + 16 * ct + 4 * q] = pkb;
  }
  if (q == 0) {
    float* mlb = Ml + (size_t)blk * 256;
    mlb[ra * 2] = ma; mlb[ra * 2 + 1] = la;
    mlb[rb * 2] = mb; mlb[rb * 2 + 1] = lb;
  }
}

// ---------------------------------------------------------------------------
// merge: combine 4 split-K partials -> Ot = [B][N][64] bf16 (adds bv, /l).
// grid 288 blocks x 256 thr; thread = (row, 32-col half).
// ---------------------------------------------------------------------------
extern "C" __global__ __launch_bounds__(256) void merge_kernel(
    const u16* __restrict__ Opart, const float* __restrict__ Ml,
    const float* __restrict__ bv, u16* __restrict__ Ot) {
  int b = blockIdx.x / FTILES, tile = blockIdx.x % FTILES;
  int t = threadIdx.x;
  int row = t >> 1, half = t & 1, c0 = 32 * half;
  int p0 = (b * FTILES + tile) * NCHUNK;
  float mc[4], lc[4];
#pragma unroll
  for (int ch = 0; ch < 4; ch++) {
    const float* mlb = Ml + (size_t)(p0 + ch) * 256 + row * 2;
    mc[ch] = mlb[0]; lc[ch] = mlb[1];
  }
  float mstar = fmaxf(fmaxf(mc[0], mc[1]), fmaxf(mc[2], mc[3]));
  float wch[4], L = 0.f;
#pragma unroll
  for (int ch = 0; ch < 4; ch++) { wch[ch] = __builtin_amdgcn_exp2f(mc[ch] - mstar); L += wch[ch] * lc[ch]; }
  float rl = 1.0f / L;
  float acc[32];
#pragma unroll
  for (int j = 0; j < 32; j++) acc[j] = 0.f;
#pragma unroll
  for (int ch = 0; ch < 4; ch++) {
    const u16* op = Opart + ((size_t)(p0 + ch) * 128 + row) * 64 + c0;
    float wc = wch[ch];
#pragma unroll
    for (int v = 0; v < 4; v++) {
      u16x8 d = *(const u16x8*)(op + v * 8);
#pragma unroll
      for (int j = 0; j < 8; j++) acc[v * 8 + j] += wc * bf2f(d[j]);
    }
  }
  u16* dst = Ot + (size_t)(b * NN + tile * 128 + row) * 64 + c0;
#pragma unroll
  for (int v = 0; v < 4; v++) {
    u16x8 pk;
#pragma unroll
    for (int j = 0; j < 8; j++) pk[j] = f2bf(acc[v * 8 + j] * rl + bv[c0 + v * 8 + j]);
    *(u16x8*)(dst + v * 8) = pk;
  }
}

// ---------------------------------------------------------------------------
// out: out = x + Wo*o + bo via MFMA, float4 stores.
// ---------------------------------------------------------------------------
extern "C" __global__ __launch_bounds__(256, 4) void out_kernel(
    const float* __restrict__ x, const u16* __restrict__ wob, const float* __restrict__ bo,
    const u16* __restrict__ Ot, float* __restrict__ out) {
  int b = blockIdx.x / NTILES, tile = blockIdx.x % NTILES;
  int t = threadIdx.x;
  int w = t >> 6, lane = t & 63, q = lane >> 4, ln = lane & 15;
  int n0w = tile * 64 + 16 * w;
  const u16* op = Ot + (size_t)(b * NN + n0w + ln) * 64 + q * 8;
  bhalf8 a0 = *(const bhalf8*)op;
  bhalf8 a1 = *(const bhalf8*)(op + 32);
#pragma unroll
  for (int ct = 0; ct < 4; ct++) {
    int wrow = (16 * ct + ln) * 64;
    bhalf8 b0 = *(const bhalf8*)&wob[wrow + q * 8];
    bhalf8 b1 = *(const bhalf8*)&wob[wrow + 32 + q * 8];
    f32x4 d = {0.f, 0.f, 0.f, 0.f};
    d = MFMA16(a0, b0, d);
    d = MFMA16(a1, b1, d);
    int co = 16 * ct + ln;
    size_t base = (size_t)(b * 64 + co) * NN + n0w + 4 * q;
    f32x4 xv = *(const f32x4*)&x[base];
    float bc = bo[co];
    f32x4 ov;
#pragma unroll
    for (int r = 0; r < 4; r++) ov[r] = xv[r] + bc + d[r];
    *(f32x4*)&out[base] = ov;
  }
}

extern "C" void kernel_launch(void* const* d_in, const int* in_sizes, int n_in,
                              void* d_out, int out_size, void* d_ws, size_t ws_size,
                              hipStream_t stream) {
  (void)in_sizes; (void)n_in; (void)out_size; (void)ws_size;
  const float* x  = (const float*)d_in[0];
  const float* wq = (const float*)d_in[1];
  const float* bq = (const float*)d_in[2];
  const float* wk = (const float*)d_in[3];
  const float* bk = (const float*)d_in[4];
  const float* wv = (const float*)d_in[5];
  const float* bv = (const float*)d_in[6];
  const float* wo = (const float*)d_in[7];
  const float* bo = (const float*)d_in[8];
  float* out = (float*)d_out;
  char* ws = (char*)d_ws;
  // workspace layout (16B aligned), ~39.2 MB total
  float* mean = (float*)ws;                   // 256 f32
  float* rstd = (float*)(ws + 1024);          // 256 f32
  u16* wbf = (u16*)(ws + 2048);               // 16384 bf16
  u16* Qt = (u16*)(ws + 36864);               // [B][N][64] bf16  4.72MB
  u16* Kt = Qt + (size_t)BB * NN * 64;
  u16* Vt = Kt + (size_t)BB * NN * 64;
  u16* Ot = Vt + (size_t)BB * NN * 64;
  u16* Opart = Ot + (size_t)BB * NN * 64;     // 1152 * 128*64 bf16 = 18.9MB
  float* Ml = (float*)(Opart + (size_t)BB * FTILES * NCHUNK * 128 * 64);  // 1152*256 f32 = 1.18MB
  const u16* wqb = wbf;
  const u16* wkb = wbf + 4096;
  const u16* wvb = wbf + 8192;
  const u16* wob = wbf + 12288;

  prep_kernel<<<320, 256, 0, stream>>>(x, wq, wk, wv, wo, mean, rstd, wbf);
  qkv_kernel<<<BB * NTILES, 256, 0, stream>>>(x, mean, rstd, wqb, wkb, wvb, bq, bk, Qt, Kt, Vt);
  flash_kernel<<<BB * FTILES * NCHUNK, 256, 0, stream>>>(Qt, Kt, Vt, Opart, Ml);
  merge_kernel<<<BB * FTILES, 256, 0, stream>>>(Opart, Ml, bv, Ot);
  out_kernel<<<BB * NTILES, 256, 0, stream>>>(x, wob, bo, Ot, out);
}